// Round 5
// baseline (385.192 us; speedup 1.0000x reference)
//
#include <hip/hip_runtime.h>
#include <hip/hip_bf16.h>

typedef int v4i  __attribute__((ext_vector_type(4)));
typedef int v16i __attribute__((ext_vector_type(16)));

#define M_DIM 16384
#define N_DIM 4096
#define K_DIM 4096
#define BM 256
#define BN 256
#define BKB 128                 // K-bytes per tile
#define NT (K_DIM / BKB)        // 32 K-tiles

// ---------------- activation fake-quant: f32 -> i8 ----------------
// r5: division replaced by reciprocal-multiply. With no fast-math, x/s emits
// a ~30cyc div sequence x4 per 16B => VALU-bound (~130cyc VALU vs ~100cyc HBM
// per wave-iter). inv_s hoisted => BW-bound. (1-ulp rint flips ~ s*alpha ~
// 6e-4 per element, far under tolerance.)
__global__ void quant_x_kernel(const float4* __restrict__ x, int* __restrict__ q,
                               const float* __restrict__ act_scale, int n4) {
  const float s = fmaxf(act_scale[0], 1e-5f);
  const float inv_s = 1.0f / s;
  int i = blockIdx.x * blockDim.x + threadIdx.x;
  const int stride = gridDim.x * blockDim.x;
  for (; i < n4; i += stride) {
    float4 v = x[i];
    int b0 = (int)fminf(fmaxf(rintf(v.x * inv_s), -127.f), 127.f);
    int b1 = (int)fminf(fmaxf(rintf(v.y * inv_s), -127.f), 127.f);
    int b2 = (int)fminf(fmaxf(rintf(v.z * inv_s), -127.f), 127.f);
    int b3 = (int)fminf(fmaxf(rintf(v.w * inv_s), -127.f), 127.f);
    q[i] = (b0 & 0xff) | ((b1 & 0xff) << 8) | ((b2 & 0xff) << 16) | ((b3 & 0xff) << 24);
  }
}

// ---------------- ternary weight repack: i32 {0,1,2} -> i8 {-1,0,1} ----------------
__global__ void pack_w_kernel(const int4* __restrict__ w, int* __restrict__ q, int n4) {
  int i = blockIdx.x * blockDim.x + threadIdx.x;
  const int stride = gridDim.x * blockDim.x;
  for (; i < n4; i += stride) {
    int4 v = w[i];
    q[i] = ((v.x - 1) & 0xff) | (((v.y - 1) & 0xff) << 8) |
           (((v.z - 1) & 0xff) << 16) | (((v.w - 1) & 0xff) << 24);
  }
}

// ---- i8 GEMM. r4 post-mortem: rotation = r1 exactly (compiler already
// hoists independent ds_reads; per-wave latency not the limiter). Kernel sits
// at the sum-of-pipes floor (LDS ~3072 + MFMA ~2611 + drain ~ 5380cyc/tile).
// THIS ROUND (demand cut): 16x16x64 -> 32x32x32 i8 MFMA. +12% matrix rate
// (4404 vs 3944 TOPS ubench) and HALF the MFMA instruction count (32 vs 64
// per wave-tile) => MFMA pipe 2611->2342cyc, fewer issue slots/waitcnts
// competing with co-wave ds_read issue. LDS stored layout, XOR swizzle,
// staging path, read counts (A 16 + B 8 per wave-tile), acc budget (128) all
// UNCHANGED. New fragment mapping (derived from verified 32x32 layouts):
//   A: row = lane&31, 16B k-chunk = ks*2 + (lane>>5), LDS chunk ^= row&7
//   B: mirrors A with N-rows; conflict-free per 8-lane group (rows span &7)
//   C/D: col = lane&31, row = (reg&3) + 8*(reg>>2) + 4*(lane>>5)  [m74/m101]
__global__ __launch_bounds__(512, 2) void bitlinear_gemm(
    const signed char* __restrict__ A,   // [M][K] i8
    const signed char* __restrict__ B,   // [N][K] i8
    const float* __restrict__ bias,
    const float* __restrict__ alpha_p,
    const float* __restrict__ act_scale_p,
    float* __restrict__ out) {
  __shared__ __align__(16) signed char As[2][BM * BKB];   // 2 x 32 KiB
  __shared__ __align__(16) signed char Bs[2][BN * BKB];   // 2 x 32 KiB

  const int t = threadIdx.x;
  const int lane = t & 63, wid = t >> 6;
  const int wm = wid >> 2, wn = wid & 3;       // 2M x 4N waves
  const int l31 = lane & 31, l5 = lane >> 5;

  // XCD-aware bijective swizzle (nwg=1024, divisible by 8)
  const int nwg = (M_DIM / BM) * (N_DIM / BN);
  const int wg = (blockIdx.x & 7) * (nwg >> 3) + (blockIdx.x >> 3);
  const int bm = wg / (N_DIM / BN);
  const int bn = wg % (N_DIM / BN);

  // ---- reg-staging addressing: LINEAR global loads, SWIZZLED ds_write ----
  const signed char* aGl = A + ((size_t)(bm * BM + (t >> 3))) * K_DIM + (t & 7) * 16;
  const signed char* bGl = B + ((size_t)(bn * BN + (t >> 3))) * K_DIM + (t & 7) * 16;
  // LDS write offset: row*128 + (chunk ^ (row&7))*16   (stored layout unchanged)
  const int wrOff = (t >> 3) * 128 + (((t & 7) ^ ((t >> 3) & 7)) * 16);

  v4i sA[4], sB[4];   // staging registers (one tile in flight)

#define GL_A(u, P) sA[u] = *(const v4i*)((P) + (size_t)((u) * 64) * K_DIM)
#define GL_B(u, P) sB[u] = *(const v4i*)((P) + (size_t)((u) * 64) * K_DIM)
#define WR_A(BUF) { _Pragma("unroll") for (int u = 0; u < 4; ++u) \
    *(v4i*)&As[BUF][u * 8192 + wrOff] = sA[u]; }
#define WR_B(BUF) { _Pragma("unroll") for (int u = 0; u < 4; ++u) \
    *(v4i*)&Bs[BUF][u * 8192 + wrOff] = sB[u]; }

  // ---- fragment read addressing (32x32 mapping, zero-conflict XOR layout) ----
  const int x7 = l31 & 7;
  // 16B chunk within the 128B row for kstep ks: (ks*2 + l5) ^ x7
#define CS(ks) ((((ks) * 2 + l5) ^ x7) * 16)
  const int aRd = (wm * 128 + l31) * BKB;   // + mt*32*128
  const int bRd = (wn * 64 + l31) * BKB;    // + nt*32*128

  v16i acc[4][2] = {};   // [mt][nt], 32x32 tiles; 128 acc regs total
  v4i bF[2][4];          // [nt][ks]
  v4i aF[4];             // [ks], current m-subtile

#define LOAD_B32(buf) \
  { _Pragma("unroll") for (int nt = 0; nt < 2; ++nt) { \
      _Pragma("unroll") for (int ks = 0; ks < 4; ++ks) { \
        bF[nt][ks] = *(const v4i*)&Bs[buf][bRd + nt * 4096 + CS(ks)]; } } }

#define LOAD_A32(buf, mt) \
  { _Pragma("unroll") for (int ks = 0; ks < 4; ++ks) { \
      aF[ks] = *(const v4i*)&As[buf][aRd + (mt) * 4096 + CS(ks)]; } }

  // 8 MFMAs: m-subtile mt against both n-subtiles, K=128 via 4 ksteps
#define MT(mt) \
  { _Pragma("unroll") for (int ks = 0; ks < 4; ++ks) { \
      acc[mt][0] = __builtin_amdgcn_mfma_i32_32x32x32_i8(aF[ks], bF[0][ks], acc[mt][0], 0, 0, 0); \
      acc[mt][1] = __builtin_amdgcn_mfma_i32_32x32x32_i8(aF[ks], bF[1][ks], acc[mt][1], 0, 0, 0); } }

#define BAR __builtin_amdgcn_s_barrier()
#define PRIO1 __builtin_amdgcn_s_setprio(1)
#define PRIO0 __builtin_amdgcn_s_setprio(0)

  // One K-tile: 4 m-subtiles; staging GLs spread early, WRs late (hit write
  // buffer only); single lgkmcnt(0)+barrier at the flip. No intra-tile
  // barriers (r1 structure). Compiler hoists/rotates reads as regs allow.
#define TILE_BODY(BUF, PA, PB) do { \
    LOAD_B32(BUF); \
    LOAD_A32(BUF, 0); \
    GL_B(0, PB); GL_B(1, PB); \
    PRIO1; MT(0); PRIO0; \
    LOAD_A32(BUF, 1); \
    GL_B(2, PB); GL_B(3, PB); \
    PRIO1; MT(1); PRIO0; \
    LOAD_A32(BUF, 2); \
    GL_A(0, PA); GL_A(1, PA); GL_A(2, PA); GL_A(3, PA); \
    PRIO1; MT(2); PRIO0; \
    WR_B(BUF^1); \
    LOAD_A32(BUF, 3); \
    PRIO1; MT(3); PRIO0; \
    WR_A(BUF^1); \
    asm volatile("s_waitcnt lgkmcnt(0)" ::: "memory"); \
    BAR; \
  } while (0)

  // ---- prologue: load + write tile 0 ----
  GL_B(0, bGl); GL_B(1, bGl); GL_B(2, bGl); GL_B(3, bGl);
  GL_A(0, aGl); GL_A(1, aGl); GL_A(2, aGl); GL_A(3, aGl);
  asm volatile("s_waitcnt vmcnt(0)" ::: "memory");
  WR_B(0); WR_A(0);
  asm volatile("s_waitcnt lgkmcnt(0)" ::: "memory");
  BAR;
  __builtin_amdgcn_sched_barrier(0);

  // ---- main loop: 2 K-tiles per iteration, compile-time buffer selection ----
  const signed char* aGk = aGl;
  const signed char* bGk = bGl;
  for (int it = 0; it < NT / 2 - 1; ++it) {
    TILE_BODY(0, aGk + BKB,     bGk + BKB);       // tile 2it,   load 2it+1
    TILE_BODY(1, aGk + 2 * BKB, bGk + 2 * BKB);   // tile 2it+1, load 2it+2
    aGk += 2 * BKB; bGk += 2 * BKB;
  }
  TILE_BODY(0, aGk + BKB, bGk + BKB);             // tile 30, load 31
  TILE_BODY(1, aGk + BKB, bGk + BKB);             // tile 31, re-load 31 (dead write to buf0)

  // ---- epilogue: out = acc * (clamped_act_scale * alpha) + bias ----
  // C/D 32x32: col = lane&31, row = (reg&3) + 8*(reg>>2) + 4*(lane>>5)
  const float sA_ = fmaxf(act_scale_p[0], 1e-5f) * alpha_p[0];
  const int gn0 = bn * BN + wn * 64 + l31;
  const int gm0 = bm * BM + wm * 128 + 4 * l5;
#pragma unroll
  for (int nt = 0; nt < 2; ++nt) {
    const float bv = bias[gn0 + nt * 32];
#pragma unroll
    for (int mt = 0; mt < 4; ++mt) {
#pragma unroll
      for (int r = 0; r < 16; ++r) {
        const int gm = gm0 + mt * 32 + (r & 3) + 8 * (r >> 2);
        out[(size_t)gm * N_DIM + gn0 + nt * 32] = (float)acc[mt][nt][r] * sA_ + bv;
      }
    }
  }
}

extern "C" void kernel_launch(void* const* d_in, const int* in_sizes, int n_in,
                              void* d_out, int out_size, void* d_ws, size_t ws_size,
                              hipStream_t stream) {
  const float* x      = (const float*)d_in[0];
  const int*   pw     = (const int*)d_in[1];
  const float* alpha  = (const float*)d_in[2];
  const float* act_sc = (const float*)d_in[3];
  const float* bias   = (const float*)d_in[4];
  float* out = (float*)d_out;

  signed char* x8 = (signed char*)d_ws;                          // 64 MiB
  signed char* w8 = (signed char*)d_ws + (size_t)M_DIM * K_DIM;  // 16 MiB

  quant_x_kernel<<<2048, 256, 0, stream>>>((const float4*)x, (int*)x8, act_sc, M_DIM * K_DIM / 4);
  pack_w_kernel<<<2048, 256, 0, stream>>>((const int4*)pw, (int*)w8, N_DIM * K_DIM / 4);

  dim3 grid((M_DIM / BM) * (N_DIM / BN));   // 1024 blocks, 1-D for XCD swizzle
  bitlinear_gemm<<<grid, 512, 0, stream>>>(x8, w8, bias, alpha, act_sc, out);
}

// Round 6
// 374.379 us; speedup vs baseline: 1.0289x; 1.0289x over previous
//
#include <hip/hip_runtime.h>
#include <hip/hip_bf16.h>

typedef int v4i __attribute__((ext_vector_type(4)));

#define M_DIM 16384
#define N_DIM 4096
#define K_DIM 4096
#define BM 256
#define BN 256
#define BKB 128                 // K-bytes per tile
#define NT (K_DIM / BKB)        // 32 K-tiles

#define QBLK 2048               // quant-x blocks in fused prep
#define PBLK 512                // pack-w blocks in fused prep

// ---- fused pre-pass: grid-partitioned quant(x) || pack(w). Both are
// BW-bound streams (quant: 320MiB after r5's reciprocal fix; pack: 80MiB);
// serial launches cost ~86us vs ~64us aggregate-BW floor. One launch, block
// ranges sized so per-block bytes match (~160KiB each) -> overlap + one less
// launch gap.
__global__ void prep_kernel(const float4* __restrict__ x, int* __restrict__ qx, int n4x,
                            const int4* __restrict__ w, int* __restrict__ qw, int n4w,
                            const float* __restrict__ act_scale) {
  if (blockIdx.x < QBLK) {
    const float s = fmaxf(act_scale[0], 1e-5f);
    const float inv_s = 1.0f / s;   // r5: reciprocal-multiply (div was VALU-bound)
    int i = blockIdx.x * blockDim.x + threadIdx.x;
    const int stride = QBLK * blockDim.x;
    for (; i < n4x; i += stride) {
      float4 v = x[i];
      int b0 = (int)fminf(fmaxf(rintf(v.x * inv_s), -127.f), 127.f);
      int b1 = (int)fminf(fmaxf(rintf(v.y * inv_s), -127.f), 127.f);
      int b2 = (int)fminf(fmaxf(rintf(v.z * inv_s), -127.f), 127.f);
      int b3 = (int)fminf(fmaxf(rintf(v.w * inv_s), -127.f), 127.f);
      qx[i] = (b0 & 0xff) | ((b1 & 0xff) << 8) | ((b2 & 0xff) << 16) | ((b3 & 0xff) << 24);
    }
  } else {
    int i = (blockIdx.x - QBLK) * blockDim.x + threadIdx.x;
    const int stride = PBLK * blockDim.x;
    for (; i < n4w; i += stride) {
      int4 v = w[i];
      qw[i] = ((v.x - 1) & 0xff) | (((v.y - 1) & 0xff) << 8) |
              (((v.z - 1) & 0xff) << 16) | (((v.w - 1) & 0xff) << 24);
    }
  }
}

// ---- i8 GEMM: REVERTED to the r1 champion (285us, 0 bank conflicts).
// r5 post-mortem: 32x32x32 swap produced 2.5e7 deterministic bank conflicts
// (source-level octet analysis says conflict-free -> emitted reads diverge
// from source model under v16i register pressure; unresolvable without
// disasm). r1/r4 facts: MfmaUtil ~41%, LDS util ~57% -> latency-bound at
// 2 waves/SIMD; 128-reg acc caps occupancy at 8 waves/CU, and occupancy
// redesigns raise LDS instr demand >= 33% (arithmetic wash). ~285us is this
// structure's floor.
__global__ __launch_bounds__(512, 2) void bitlinear_gemm(
    const signed char* __restrict__ A,   // [M][K] i8
    const signed char* __restrict__ B,   // [N][K] i8
    const float* __restrict__ bias,
    const float* __restrict__ alpha_p,
    const float* __restrict__ act_scale_p,
    float* __restrict__ out) {
  __shared__ __align__(16) signed char As[2][BM * BKB];   // 2 x 32 KiB
  __shared__ __align__(16) signed char Bs[2][BN * BKB];   // 2 x 32 KiB

  const int t = threadIdx.x;
  const int lane = t & 63, wid = t >> 6;
  const int wm = wid >> 2, wn = wid & 3;       // 2M x 4N waves
  const int l15 = lane & 15, l4 = lane >> 4;

  // XCD-aware bijective swizzle (nwg=1024, divisible by 8)
  const int nwg = (M_DIM / BM) * (N_DIM / BN);
  const int wg = (blockIdx.x & 7) * (nwg >> 3) + (blockIdx.x >> 3);
  const int bm = wg / (N_DIM / BN);
  const int bn = wg % (N_DIM / BN);

  // ---- reg-staging addressing: LINEAR global loads, SWIZZLED ds_write ----
  const signed char* aGl = A + ((size_t)(bm * BM + (t >> 3))) * K_DIM + (t & 7) * 16;
  const signed char* bGl = B + ((size_t)(bn * BN + (t >> 3))) * K_DIM + (t & 7) * 16;
  // LDS write offset: row*128 + (chunk ^ (row&7))*16
  const int wrOff = (t >> 3) * 128 + (((t & 7) ^ ((t >> 3) & 7)) * 16);

  v4i sA[4], sB[4];   // staging registers (one tile in flight)

#define GL_A(u, P) sA[u] = *(const v4i*)((P) + (size_t)((u) * 64) * K_DIM)
#define GL_B(u, P) sB[u] = *(const v4i*)((P) + (size_t)((u) * 64) * K_DIM)
#define WR_A(BUF) { _Pragma("unroll") for (int u = 0; u < 4; ++u) \
    *(v4i*)&As[BUF][u * 8192 + wrOff] = sA[u]; }
#define WR_B(BUF) { _Pragma("unroll") for (int u = 0; u < 4; ++u) \
    *(v4i*)&Bs[BUF][u * 8192 + wrOff] = sB[u]; }

  // ---- fragment read addressing (zero-conflict XOR layout) ----
  const int l7 = l15 & 7;
  const int soK0 = ((0 + l4) ^ l7) * 16;   // kstep 0 chunk
  const int soK1 = ((4 + l4) ^ l7) * 16;   // kstep 1 chunk
  const int aRd = (wm * 128 + l15) * BKB;
  const int bRd = (wn * 64 + l15) * BKB;

  v4i acc[8][4] = {};
  v4i bF[4][2], aF[2][2];

#define LOAD_B(buf) \
  { _Pragma("unroll") for (int nc = 0; nc < 4; ++nc) { \
      bF[nc][0] = *(const v4i*)&Bs[buf][bRd + nc * 2048 + soK0]; \
      bF[nc][1] = *(const v4i*)&Bs[buf][bRd + nc * 2048 + soK1]; } }

#define LOAD_A(buf, q) \
  aF[0][0] = *(const v4i*)&As[buf][aRd + (2*(q)) * 2048 + soK0]; \
  aF[0][1] = *(const v4i*)&As[buf][aRd + (2*(q)) * 2048 + soK1]; \
  aF[1][0] = *(const v4i*)&As[buf][aRd + (2*(q)+1) * 2048 + soK0]; \
  aF[1][1] = *(const v4i*)&As[buf][aRd + (2*(q)+1) * 2048 + soK1];

#define MFMA_Q(q) \
  { _Pragma("unroll") for (int nc = 0; nc < 4; ++nc) { \
      acc[2*(q)][nc]   = __builtin_amdgcn_mfma_i32_16x16x64_i8(aF[0][0], bF[nc][0], acc[2*(q)][nc], 0, 0, 0); \
      acc[2*(q)][nc]   = __builtin_amdgcn_mfma_i32_16x16x64_i8(aF[0][1], bF[nc][1], acc[2*(q)][nc], 0, 0, 0); \
      acc[2*(q)+1][nc] = __builtin_amdgcn_mfma_i32_16x16x64_i8(aF[1][0], bF[nc][0], acc[2*(q)+1][nc], 0, 0, 0); \
      acc[2*(q)+1][nc] = __builtin_amdgcn_mfma_i32_16x16x64_i8(aF[1][1], bF[nc][1], acc[2*(q)+1][nc], 0, 0, 0); } }

#define BAR __builtin_amdgcn_s_barrier()

  // One K-tile: 4 quarters in program order, no intra-tile barriers; single
  // lgkmcnt(0)+barrier at the buffer flip (verified 285us schedule).
#define TILE_BODY(BUF, PA, PB) do { \
    LOAD_B(BUF); LOAD_A(BUF, 0); \
    GL_B(0, PB); GL_B(1, PB); \
    __builtin_amdgcn_s_setprio(1); MFMA_Q(0); __builtin_amdgcn_s_setprio(0); \
    LOAD_A(BUF, 1); \
    GL_B(2, PB); GL_B(3, PB); \
    __builtin_amdgcn_s_setprio(1); MFMA_Q(1); __builtin_amdgcn_s_setprio(0); \
    LOAD_A(BUF, 2); \
    GL_A(0, PA); GL_A(1, PA); GL_A(2, PA); GL_A(3, PA); \
    __builtin_amdgcn_s_setprio(1); MFMA_Q(2); __builtin_amdgcn_s_setprio(0); \
    WR_B(BUF^1); \
    LOAD_A(BUF, 3); \
    __builtin_amdgcn_s_setprio(1); MFMA_Q(3); __builtin_amdgcn_s_setprio(0); \
    WR_A(BUF^1); \
    asm volatile("s_waitcnt lgkmcnt(0)" ::: "memory"); \
    BAR; \
  } while (0)

  // ---- prologue: load + write tile 0 ----
  GL_B(0, bGl); GL_B(1, bGl); GL_B(2, bGl); GL_B(3, bGl);
  GL_A(0, aGl); GL_A(1, aGl); GL_A(2, aGl); GL_A(3, aGl);
  asm volatile("s_waitcnt vmcnt(0)" ::: "memory");
  WR_B(0); WR_A(0);
  asm volatile("s_waitcnt lgkmcnt(0)" ::: "memory");
  BAR;
  __builtin_amdgcn_sched_barrier(0);

  // ---- main loop: 2 K-tiles per iteration, compile-time buffer selection ----
  const signed char* aGk = aGl;
  const signed char* bGk = bGl;
  for (int it = 0; it < NT / 2 - 1; ++it) {
    TILE_BODY(0, aGk + BKB,     bGk + BKB);       // tile 2it,   load 2it+1
    TILE_BODY(1, aGk + 2 * BKB, bGk + 2 * BKB);   // tile 2it+1, load 2it+2
    aGk += 2 * BKB; bGk += 2 * BKB;
  }
  TILE_BODY(0, aGk + BKB, bGk + BKB);             // tile 30, load 31
  TILE_BODY(1, aGk + BKB, bGk + BKB);             // tile 31, re-load 31 (dead write to buf0)

  // ---- epilogue: out = acc * (clamped_act_scale * alpha) + bias ----
  const float sA_ = fmaxf(act_scale_p[0], 1e-5f) * alpha_p[0];
  const int gn0 = bn * BN + wn * 64 + l15;
  const int gm0 = bm * BM + wm * 128 + l4 * 4;
#pragma unroll
  for (int nc = 0; nc < 4; ++nc) {
    const float bv = bias[gn0 + nc * 16];
#pragma unroll
    for (int mr = 0; mr < 8; ++mr) {
#pragma unroll
      for (int r = 0; r < 4; ++r) {
        const int gm = gm0 + mr * 16 + r;          // C/D: col=lane&15, row=(lane>>4)*4+reg
        out[(size_t)gm * N_DIM + gn0 + nc * 16] = (float)acc[mr][nc][r] * sA_ + bv;
      }
    }
  }
}

extern "C" void kernel_launch(void* const* d_in, const int* in_sizes, int n_in,
                              void* d_out, int out_size, void* d_ws, size_t ws_size,
                              hipStream_t stream) {
  const float* x      = (const float*)d_in[0];
  const int*   pw     = (const int*)d_in[1];
  const float* alpha  = (const float*)d_in[2];
  const float* act_sc = (const float*)d_in[3];
  const float* bias   = (const float*)d_in[4];
  float* out = (float*)d_out;

  signed char* x8 = (signed char*)d_ws;                          // 64 MiB
  signed char* w8 = (signed char*)d_ws + (size_t)M_DIM * K_DIM;  // 16 MiB

  prep_kernel<<<QBLK + PBLK, 256, 0, stream>>>(
      (const float4*)x, (int*)x8, M_DIM * K_DIM / 4,
      (const int4*)pw, (int*)w8, N_DIM * K_DIM / 4, act_sc);

  dim3 grid((M_DIM / BM) * (N_DIM / BN));   // 1024 blocks, 1-D for XCD swizzle
  bitlinear_gemm<<<grid, 512, 0, stream>>>(x8, w8, bias, alpha, act_sc, out);
}